// Round 1
// baseline (2956.926 us; speedup 1.0000x reference)
//
#include <hip/hip_runtime.h>
#include <math.h>

// ---- problem constants ----
#define NM 50000
#define ND 10000
#define NA 25000
#define E_DM 150000
#define E_AM 300000
#define HID 256
#define HEADS 8
#define HD 32
#define FIN 1024
#define SCALE 0.17677669529663687f  // 1/sqrt(32)

__device__ __forceinline__ int ord_of_float(float f) {
    int b = __float_as_int(f);
    return b < 0 ? (b ^ 0x7FFFFFFF) : b;
}
__device__ __forceinline__ float float_of_ord(int i) {
    return __int_as_float(i < 0 ? (i ^ 0x7FFFFFFF) : i);
}

// Fold per-head relation matrix a[8][32][32] into W[256][256] (and bias).
// Wf[r][h*32+f] = sum_d W[r][h*32+d] * a[h][d][f];  blockIdx.x==256 row does bias.
__global__ void fold_w(const float* __restrict__ W, const float* __restrict__ b,
                       const float* __restrict__ a, float* __restrict__ Wf,
                       float* __restrict__ bf) {
    int c = threadIdx.x;            // 0..255
    int h = c >> 5, f = c & 31;
    int r = blockIdx.x;             // 0..256
    float acc = 0.f;
    if (r < HID) {
        #pragma unroll
        for (int d = 0; d < HD; ++d)
            acc += W[r * HID + h * HD + d] * a[(h * HD + d) * HD + f];
        Wf[r * HID + c] = acc;
    } else {
        #pragma unroll
        for (int d = 0; d < HD; ++d)
            acc += b[h * HD + d] * a[(h * HD + d) * HD + f];
        bf[c] = acc;
    }
}

// C[M,256] = A[M,K] @ B[K,256] + bias, optional gelu+gated-skip epilogue.
// 64-row tile x full 256 cols, 256 threads, each thread 4x16.
__launch_bounds__(256)
__global__ void gemm_n256(const float* __restrict__ A, const float* __restrict__ B,
                          const float* __restrict__ bias, float* __restrict__ C,
                          int M, int K, int epi,
                          const float* __restrict__ hskip, const float* __restrict__ gate) {
    __shared__ __align__(16) float sA[16][64];
    __shared__ __align__(16) float sB[16][256];
    int tid = threadIdx.x;
    int bm = blockIdx.x * 64;
    int r0 = (tid >> 4) * 4;      // 0..60
    int c0 = (tid & 15) * 16;     // 0..240
    float acc[4][16];
    #pragma unroll
    for (int i = 0; i < 4; ++i)
        #pragma unroll
        for (int j = 0; j < 16; ++j) acc[i][j] = 0.f;

    int arow = tid >> 2;          // 0..63
    int akc  = (tid & 3) * 4;     // 0,4,8,12
    int brow = tid >> 4;          // 0..15
    int bcol = (tid & 15) * 16;   // 0..240

    for (int k0 = 0; k0 < K; k0 += 16) {
        float4 av;
        int gr = bm + arow;
        if (gr < M) av = *(const float4*)(A + (size_t)gr * K + k0 + akc);
        else av = make_float4(0.f, 0.f, 0.f, 0.f);
        sA[akc + 0][arow] = av.x;
        sA[akc + 1][arow] = av.y;
        sA[akc + 2][arow] = av.z;
        sA[akc + 3][arow] = av.w;

        const float* Bp = B + (size_t)(k0 + brow) * HID + bcol;
        float4 b0 = *(const float4*)(Bp + 0);
        float4 b1 = *(const float4*)(Bp + 4);
        float4 b2 = *(const float4*)(Bp + 8);
        float4 b3 = *(const float4*)(Bp + 12);
        *(float4*)&sB[brow][bcol + 0]  = b0;
        *(float4*)&sB[brow][bcol + 4]  = b1;
        *(float4*)&sB[brow][bcol + 8]  = b2;
        *(float4*)&sB[brow][bcol + 12] = b3;
        __syncthreads();

        #pragma unroll
        for (int k = 0; k < 16; ++k) {
            float4 a4 = *(const float4*)&sA[k][r0];
            float bv[16];
            *(float4*)&bv[0]  = *(const float4*)&sB[k][c0 + 0];
            *(float4*)&bv[4]  = *(const float4*)&sB[k][c0 + 4];
            *(float4*)&bv[8]  = *(const float4*)&sB[k][c0 + 8];
            *(float4*)&bv[12] = *(const float4*)&sB[k][c0 + 12];
            #pragma unroll
            for (int j = 0; j < 16; ++j) {
                acc[0][j] += a4.x * bv[j];
                acc[1][j] += a4.y * bv[j];
                acc[2][j] += a4.z * bv[j];
                acc[3][j] += a4.w * bv[j];
            }
        }
        __syncthreads();
    }

    float beta = 0.f;
    if (epi == 1) beta = 1.f / (1.f + expf(-gate[0]));
    for (int i = 0; i < 4; ++i) {
        int gr = bm + r0 + i;
        if (gr >= M) break;
        #pragma unroll
        for (int j = 0; j < 16; ++j) {
            float v = acc[i][j] + bias[c0 + j];
            if (epi == 1) {
                float x = v;
                float x3 = x * x * x;
                float g = 0.5f * x * (1.f + tanhf(0.7978845608028654f * (x + 0.044715f * x3)));
                v = beta * g + (1.f - beta) * hskip[(size_t)gr * HID + c0 + j];
            }
            C[(size_t)gr * HID + c0 + j] = v;
        }
    }
}

__global__ void init_amax(int* __restrict__ amax, int n) {
    int i = blockIdx.x * 256 + threadIdx.x;
    if (i < n) amax[i] = 0x80000000;  // ordered-int -inf
}

// One block per edge. 32-lane groups compute per-head dot(q[dst], kt[src]).
__launch_bounds__(256)
__global__ void edge_score(const int* __restrict__ src, const int* __restrict__ dst,
                           const float* __restrict__ kt, const float* __restrict__ q,
                           const float* __restrict__ prio, float* __restrict__ al,
                           int* __restrict__ amax, int E) {
    int e = blockIdx.x;
    if (e >= E) return;
    int t = threadIdx.x;
    int h = t >> 5, f = t & 31;
    int s = src[e], d = dst[e];
    float prod = q[(size_t)d * HID + t] * kt[(size_t)s * HID + t];
    #pragma unroll
    for (int off = 16; off > 0; off >>= 1) prod += __shfl_xor(prod, off);
    if (f == 0) {
        float a = prod * prio[h] * SCALE;
        al[(size_t)e * HEADS + h] = a;
        atomicMax(&amax[d * HEADS + h], ord_of_float(a));
    }
}

// One block per edge: ex = exp(al - amax[dst]); num[dst] += ex*vt[src]; den[dst] += ex
__launch_bounds__(256)
__global__ void edge_scatter(const int* __restrict__ src, const int* __restrict__ dst,
                             const float* __restrict__ vt, const float* __restrict__ al,
                             const int* __restrict__ amax, float* __restrict__ num,
                             float* __restrict__ den, int E) {
    int e = blockIdx.x;
    if (e >= E) return;
    int t = threadIdx.x;
    int h = t >> 5, f = t & 31;
    int s = src[e], d = dst[e];
    float a = al[(size_t)e * HEADS + h];
    float m = float_of_ord(amax[d * HEADS + h]);
    float ex = expf(a - m);
    atomicAdd(&num[(size_t)d * HID + t], ex * vt[(size_t)s * HID + t]);
    if (f == 0) atomicAdd(&den[d * HEADS + h], ex);
}

__global__ void finalize_agg(float* __restrict__ num, const float* __restrict__ den, int n) {
    int i = blockIdx.x * 256 + threadIdx.x;
    if (i >= n * HID) return;
    int row = i >> 8;
    int col = i & 255;
    float dv = den[row * HEADS + (col >> 5)];
    num[i] = dv > 0.f ? num[i] / dv : 0.f;
}

// out[M,4] = X[M,256] @ W[256,4] + b
__launch_bounds__(256)
__global__ void classifier(const float* __restrict__ X, const float* __restrict__ W,
                           const float* __restrict__ b, float* __restrict__ out, int M) {
    int t = threadIdx.x;
    int row = blockIdx.x * 64 + (t >> 2);
    int col = t & 3;
    if (row >= M) return;
    float acc = 0.f;
    for (int k = 0; k < HID; ++k)
        acc += X[(size_t)row * HID + k] * W[k * 4 + col];
    out[row * 4 + col] = acc + b[col];
}

extern "C" void kernel_launch(void* const* d_in, const int* in_sizes, int n_in,
                              void* d_out, int out_size, void* d_ws, size_t ws_size,
                              hipStream_t stream) {
    (void)in_sizes; (void)n_in; (void)out_size; (void)ws_size;
    // inputs (setup_inputs dict order)
    const float* x_movie    = (const float*)d_in[0];
    const float* x_director = (const float*)d_in[1];
    const float* x_actor    = (const float*)d_in[2];
    // md (3..7) and ma (13..17) are dead: only movie output is used.
    const int*   e_dm_src = (const int*)d_in[8];
    const int*   e_dm_dst = (const int*)d_in[9];
    const float* a_dm     = (const float*)d_in[10];
    const float* m_dm     = (const float*)d_in[11];
    const float* p_dm     = (const float*)d_in[12];
    const int*   e_am_src = (const int*)d_in[18];
    const int*   e_am_dst = (const int*)d_in[19];
    const float* a_am     = (const float*)d_in[20];
    const float* m_am     = (const float*)d_in[21];
    const float* p_am     = (const float*)d_in[22];
    // movie weights 23..33
    const float* W_in_m = (const float*)d_in[23];
    const float* b_in_m = (const float*)d_in[24];
    const float* Wq_m   = (const float*)d_in[27];
    const float* bq_m   = (const float*)d_in[28];
    const float* Wa_m   = (const float*)d_in[31];
    const float* ba_m   = (const float*)d_in[32];
    const float* skip_m = (const float*)d_in[33];
    // director weights 34..44
    const float* W_in_d = (const float*)d_in[34];
    const float* b_in_d = (const float*)d_in[35];
    const float* Wk_d   = (const float*)d_in[36];
    const float* bk_d   = (const float*)d_in[37];
    const float* Wv_d   = (const float*)d_in[40];
    const float* bv_d   = (const float*)d_in[41];
    // actor weights 45..55
    const float* W_in_a = (const float*)d_in[45];
    const float* b_in_a = (const float*)d_in[46];
    const float* Wk_a   = (const float*)d_in[47];
    const float* bk_a   = (const float*)d_in[48];
    const float* Wv_a   = (const float*)d_in[51];
    const float* bv_a   = (const float*)d_in[52];
    const float* W_out  = (const float*)d_in[56];
    const float* b_out  = (const float*)d_in[57];

    // workspace layout
    float* ws = (float*)d_ws;
    size_t off = 0;
    float* h_m   = ws + off; off += (size_t)NM * HID;
    float* h_d   = ws + off; off += (size_t)ND * HID;
    float* h_a   = ws + off; off += (size_t)NA * HID;
    float* q_m   = ws + off; off += (size_t)NM * HID;   // later reused as out_movie
    float* kt_dm = ws + off; off += (size_t)ND * HID;
    float* vt_dm = ws + off; off += (size_t)ND * HID;
    float* kt_am = ws + off; off += (size_t)NA * HID;
    float* vt_am = ws + off; off += (size_t)NA * HID;
    float* Wf    = ws + off; off += 4 * (size_t)HID * HID;
    float* bf    = ws + off; off += 4 * (size_t)HID;
    float* al    = ws + off; off += (size_t)(E_DM + E_AM) * HEADS;
    int*   amax  = (int*)(ws + off); off += (size_t)NM * HEADS;
    float* den   = ws + off; off += (size_t)NM * HEADS;
    float* num   = ws + off; off += (size_t)NM * HID;

    float* Wf_k_dm = Wf + 0 * HID * HID;  float* bf_k_dm = bf + 0 * HID;
    float* Wf_v_dm = Wf + 1 * HID * HID;  float* bf_v_dm = bf + 1 * HID;
    float* Wf_k_am = Wf + 2 * HID * HID;  float* bf_k_am = bf + 2 * HID;
    float* Wf_v_am = Wf + 3 * HID * HID;  float* bf_v_am = bf + 3 * HID;

    // fold relation matrices into K/V weights
    fold_w<<<257, 256, 0, stream>>>(Wk_d, bk_d, a_dm, Wf_k_dm, bf_k_dm);
    fold_w<<<257, 256, 0, stream>>>(Wv_d, bv_d, m_dm, Wf_v_dm, bf_v_dm);
    fold_w<<<257, 256, 0, stream>>>(Wk_a, bk_a, a_am, Wf_k_am, bf_k_am);
    fold_w<<<257, 256, 0, stream>>>(Wv_a, bv_a, m_am, Wf_v_am, bf_v_am);

    // h = x @ W_in + b
    gemm_n256<<<(NM + 63) / 64, 256, 0, stream>>>(x_movie,    W_in_m, b_in_m, h_m, NM, FIN, 0, nullptr, nullptr);
    gemm_n256<<<(ND + 63) / 64, 256, 0, stream>>>(x_director, W_in_d, b_in_d, h_d, ND, FIN, 0, nullptr, nullptr);
    gemm_n256<<<(NA + 63) / 64, 256, 0, stream>>>(x_actor,    W_in_a, b_in_a, h_a, NA, FIN, 0, nullptr, nullptr);

    // q for movie; folded kt/vt for director (rel dm) and actor (rel am)
    gemm_n256<<<(NM + 63) / 64, 256, 0, stream>>>(h_m, Wq_m,    bq_m,    q_m,   NM, HID, 0, nullptr, nullptr);
    gemm_n256<<<(ND + 63) / 64, 256, 0, stream>>>(h_d, Wf_k_dm, bf_k_dm, kt_dm, ND, HID, 0, nullptr, nullptr);
    gemm_n256<<<(ND + 63) / 64, 256, 0, stream>>>(h_d, Wf_v_dm, bf_v_dm, vt_dm, ND, HID, 0, nullptr, nullptr);
    gemm_n256<<<(NA + 63) / 64, 256, 0, stream>>>(h_a, Wf_k_am, bf_k_am, kt_am, NA, HID, 0, nullptr, nullptr);
    gemm_n256<<<(NA + 63) / 64, 256, 0, stream>>>(h_a, Wf_v_am, bf_v_am, vt_am, NA, HID, 0, nullptr, nullptr);

    // init accumulators (must re-init every call; harness doesn't re-poison)
    hipMemsetAsync(den, 0, (size_t)NM * HEADS * sizeof(float), stream);
    hipMemsetAsync(num, 0, (size_t)NM * HID * sizeof(float), stream);
    init_amax<<<(NM * HEADS + 255) / 256, 256, 0, stream>>>(amax, NM * HEADS);

    // edge passes (dm then am) into the shared movie-destination accumulators
    edge_score<<<E_DM, 256, 0, stream>>>(e_dm_src, e_dm_dst, kt_dm, q_m, p_dm, al, amax, E_DM);
    edge_score<<<E_AM, 256, 0, stream>>>(e_am_src, e_am_dst, kt_am, q_m, p_am,
                                         al + (size_t)E_DM * HEADS, amax, E_AM);
    edge_scatter<<<E_DM, 256, 0, stream>>>(e_dm_src, e_dm_dst, vt_dm, al, amax, num, den, E_DM);
    edge_scatter<<<E_AM, 256, 0, stream>>>(e_am_src, e_am_dst, vt_am,
                                           al + (size_t)E_DM * HEADS, amax, num, den, E_AM);
    finalize_agg<<<(NM * HID + 255) / 256, 256, 0, stream>>>(num, den, NM);

    // out_movie = beta*gelu(agg@Wa+ba) + (1-beta)*h_m   (into q_m, which is dead now)
    gemm_n256<<<(NM + 63) / 64, 256, 0, stream>>>(num, Wa_m, ba_m, q_m, NM, HID, 1, h_m, skip_m);

    // classifier
    classifier<<<(NM + 63) / 64, 256, 0, stream>>>(q_m, W_out, b_out, (float*)d_out, NM);
}

// Round 2
// 1002.578 us; speedup vs baseline: 2.9493x; 2.9493x over previous
//
#include <hip/hip_runtime.h>
#include <math.h>

// ---- problem constants ----
#define NM 50000
#define ND 10000
#define NA 25000
#define E_DM 150000
#define E_AM 300000
#define HID 256
#define HEADS 8
#define HD 32
#define FIN 1024
#define SCALE 0.17677669529663687f  // 1/sqrt(32)

typedef __attribute__((ext_vector_type(8))) short short8;
typedef __attribute__((ext_vector_type(4))) float f32x4;

__device__ __forceinline__ int ord_of_float(float f) {
    int b = __float_as_int(f);
    return b < 0 ? (b ^ 0x7FFFFFFF) : b;
}
__device__ __forceinline__ float float_of_ord(int i) {
    return __int_as_float(i < 0 ? (i ^ 0x7FFFFFFF) : i);
}
// RNE f32 -> bf16 (packed pair into one u32)
__device__ __forceinline__ unsigned int pk_bf16(float x, float y) {
    unsigned int a = __float_as_uint(x), b = __float_as_uint(y);
    a += 0x7FFFu + ((a >> 16) & 1u);
    b += 0x7FFFu + ((b >> 16) & 1u);
    return (a >> 16) | (b & 0xFFFF0000u);
}
__device__ __forceinline__ unsigned short to_bf16(float x) {
    unsigned int a = __float_as_uint(x);
    a += 0x7FFFu + ((a >> 16) & 1u);
    return (unsigned short)(a >> 16);
}

// Fold per-head relation matrix a[8][32][32] into W[256][256] (and bias).
__global__ void fold_w(const float* __restrict__ W, const float* __restrict__ b,
                       const float* __restrict__ a, float* __restrict__ Wf,
                       float* __restrict__ bf) {
    int c = threadIdx.x;            // 0..255
    int h = c >> 5, f = c & 31;
    int r = blockIdx.x;             // 0..256
    float acc = 0.f;
    if (r < HID) {
        #pragma unroll
        for (int d = 0; d < HD; ++d)
            acc += W[r * HID + h * HD + d] * a[(h * HD + d) * HD + f];
        Wf[r * HID + c] = acc;
    } else {
        #pragma unroll
        for (int d = 0; d < HD; ++d)
            acc += b[h * HD + d] * a[(h * HD + d) * HD + f];
        bf[c] = acc;
    }
}

// Transpose + convert weight fp32 [K][256] -> bf16 Bt [256][K]
__global__ void wt_prep(const float* __restrict__ W, unsigned short* __restrict__ Bt, int K) {
    __shared__ float tile[32][33];
    int k0 = blockIdx.x * 32;
    int c0 = blockIdx.y * 32;
    int t = threadIdx.x;            // 256
    int r = t >> 5, c = t & 31;
    #pragma unroll
    for (int rr = 0; rr < 32; rr += 8)
        tile[r + rr][c] = W[(size_t)(k0 + r + rr) * HID + c0 + c];
    __syncthreads();
    #pragma unroll
    for (int rr = 0; rr < 32; rr += 8) {
        int row = r + rr;           // output row (= W column)
        Bt[(size_t)(c0 + row) * K + k0 + c] = to_bf16(tile[c][row]);
    }
}

// ---- multi-descriptor MFMA GEMM: C[M,256] = A[M,K] @ B[K,256] + bias ----
// Bt is bf16 [256][K] (pre-transposed). A fp32 converted to bf16 in staging.
// Tile: BM=128 x BN=256, BK=32. 512 threads = 8 waves (2Mx4N), wave out 64x64.
struct GDesc {
    const float* A; const unsigned short* Bt; const float* bias; float* C;
    const float* hskip; const float* gate; int M; int K; int epi; int b0;
};
struct GMulti { GDesc d[5]; int nd; };

#define GBM 128
#define LDP 40   // padded row length in bf16 elems (32 + 8)

__launch_bounds__(512)
__global__ void gemm_mfma(GMulti mu) {
    __shared__ unsigned short sA[GBM * LDP];   // 10240 B
    __shared__ unsigned short sB[HID * LDP];   // 20480 B

    int bid = blockIdx.x;
    int di = 0;
    #pragma unroll
    for (int i = 1; i < 5; ++i)
        if (i < mu.nd && bid >= mu.d[i].b0) di = i;
    GDesc g = mu.d[di];
    int bm = (bid - g.b0) * GBM;
    int M = g.M, K = g.K;

    int t = threadIdx.x;
    int lane = t & 63;
    int wid = t >> 6;               // 0..7
    int wr = wid >> 2;              // 0..1
    int wc = wid & 3;               // 0..3
    int l16 = lane & 15;
    int lk = (lane >> 4) * 8;       // frag k offset: 0,8,16,24

    // staging indices
    int arow = t >> 2;              // 0..127
    int aseg = (t & 3) * 8;         // 0,8,16,24
    const float* Ap = (bm + arow < M) ? (g.A + (size_t)(bm + arow) * K + aseg) : nullptr;

    f32x4 acc[4][4];
    #pragma unroll
    for (int m = 0; m < 4; ++m)
        #pragma unroll
        for (int n = 0; n < 4; ++n) acc[m][n] = (f32x4)(0.f);

    for (int k0 = 0; k0 < K; k0 += 32) {
        // stage A (fp32 -> bf16)
        unsigned int u0 = 0, u1 = 0, u2 = 0, u3 = 0;
        if (Ap) {
            float4 a0 = *(const float4*)(Ap + k0);
            float4 a1 = *(const float4*)(Ap + k0 + 4);
            u0 = pk_bf16(a0.x, a0.y); u1 = pk_bf16(a0.z, a0.w);
            u2 = pk_bf16(a1.x, a1.y); u3 = pk_bf16(a1.z, a1.w);
        }
        *(uint4*)&sA[arow * LDP + aseg] = make_uint4(u0, u1, u2, u3);

        // stage B (already bf16, pre-transposed [256][K])
        #pragma unroll
        for (int it = 0; it < 2; ++it) {
            int c2 = t + it * 512;          // 0..1023
            int n = c2 >> 2;                // 0..255
            int sg = (c2 & 3) * 8;
            uint4 v = *(const uint4*)(g.Bt + (size_t)n * K + k0 + sg);
            *(uint4*)&sB[n * LDP + sg] = v;
        }
        __syncthreads();

        short8 af[4], bfr[4];
        #pragma unroll
        for (int m = 0; m < 4; ++m)
            af[m] = *(const short8*)&sA[(wr * 64 + m * 16 + l16) * LDP + lk];
        #pragma unroll
        for (int n = 0; n < 4; ++n)
            bfr[n] = *(const short8*)&sB[(wc * 64 + n * 16 + l16) * LDP + lk];
        #pragma unroll
        for (int m = 0; m < 4; ++m)
            #pragma unroll
            for (int n = 0; n < 4; ++n)
                acc[m][n] = __builtin_amdgcn_mfma_f32_16x16x32_bf16(af[m], bfr[n], acc[m][n], 0, 0, 0);
        __syncthreads();
    }

    float beta = 0.f;
    if (g.epi) beta = 1.f / (1.f + expf(-g.gate[0]));
    #pragma unroll
    for (int m = 0; m < 4; ++m) {
        int rb = bm + wr * 64 + m * 16 + (lane >> 4) * 4;
        #pragma unroll
        for (int j = 0; j < 4; ++j) {
            int grow = rb + j;
            if (grow >= M) continue;
            #pragma unroll
            for (int n = 0; n < 4; ++n) {
                int col = wc * 64 + n * 16 + l16;
                float v = acc[m][n][j] + g.bias[col];
                if (g.epi) {
                    float x = v;
                    float gl = 0.5f * x * (1.f + tanhf(0.7978845608028654f * (x + 0.044715f * x * x * x)));
                    v = beta * gl + (1.f - beta) * g.hskip[(size_t)grow * HID + col];
                }
                g.C[(size_t)grow * HID + col] = v;
            }
        }
    }
}

__global__ void init_amax(int* __restrict__ amax, int n) {
    int i = blockIdx.x * 256 + threadIdx.x;
    if (i < n) amax[i] = 0x80000000;
}

#define EPB 16
// 256 threads handle one edge's 256 dims; loop EPB edges per block.
__launch_bounds__(256)
__global__ void edge_score(const int* __restrict__ src, const int* __restrict__ dst,
                           const float* __restrict__ kt, const float* __restrict__ q,
                           const float* __restrict__ prio, float* __restrict__ al,
                           int* __restrict__ amax, int E) {
    int t = threadIdx.x;
    int h = t >> 5, f = t & 31;
    float pr = prio[h] * SCALE;
    int e0 = blockIdx.x * EPB;
    int e1 = min(e0 + EPB, E);
    for (int e = e0; e < e1; ++e) {
        int s = src[e], d = dst[e];
        float prod = q[(size_t)d * HID + t] * kt[(size_t)s * HID + t];
        #pragma unroll
        for (int off = 16; off > 0; off >>= 1) prod += __shfl_xor(prod, off);
        if (f == 0) {
            float a = prod * pr;
            al[(size_t)e * HEADS + h] = a;
            atomicMax(&amax[d * HEADS + h], ord_of_float(a));
        }
    }
}

__launch_bounds__(256)
__global__ void edge_scatter(const int* __restrict__ src, const int* __restrict__ dst,
                             const float* __restrict__ vt, const float* __restrict__ al,
                             const int* __restrict__ amax, float* __restrict__ num,
                             float* __restrict__ den, int E) {
    int t = threadIdx.x;
    int h = t >> 5, f = t & 31;
    int e0 = blockIdx.x * EPB;
    int e1 = min(e0 + EPB, E);
    for (int e = e0; e < e1; ++e) {
        int s = src[e], d = dst[e];
        float a = al[(size_t)e * HEADS + h];
        float m = float_of_ord(amax[d * HEADS + h]);
        float ex = expf(a - m);
        atomicAdd(&num[(size_t)d * HID + t], ex * vt[(size_t)s * HID + t]);
        if (f == 0) atomicAdd(&den[d * HEADS + h], ex);
    }
}

__global__ void finalize_agg(float* __restrict__ num, const float* __restrict__ den, int n) {
    int i = blockIdx.x * 256 + threadIdx.x;
    if (i >= n * HID) return;
    int row = i >> 8;
    int col = i & 255;
    float dv = den[row * HEADS + (col >> 5)];
    num[i] = dv > 0.f ? num[i] / dv : 0.f;
}

// out[M,4] = X[M,256] @ W[256,4] + b   — one wave per row, shuffle reduce
__launch_bounds__(256)
__global__ void classifier(const float* __restrict__ X, const float* __restrict__ W,
                           const float* __restrict__ b, float* __restrict__ out, int M) {
    int t = threadIdx.x, lane = t & 63;
    int wid = blockIdx.x * 4 + (t >> 6);
    int nw = gridDim.x * 4;
    float w0[4], w1[4], w2[4], w3[4];
    #pragma unroll
    for (int j = 0; j < 4; ++j) {
        float4 wv = *(const float4*)(W + (lane * 4 + j) * 4);
        w0[j] = wv.x; w1[j] = wv.y; w2[j] = wv.z; w3[j] = wv.w;
    }
    float b0 = b[0], b1 = b[1], b2 = b[2], b3 = b[3];
    for (int row = wid; row < M; row += nw) {
        float4 x = *(const float4*)(X + (size_t)row * HID + lane * 4);
        float s0 = x.x * w0[0] + x.y * w0[1] + x.z * w0[2] + x.w * w0[3];
        float s1 = x.x * w1[0] + x.y * w1[1] + x.z * w1[2] + x.w * w1[3];
        float s2 = x.x * w2[0] + x.y * w2[1] + x.z * w2[2] + x.w * w2[3];
        float s3 = x.x * w3[0] + x.y * w3[1] + x.z * w3[2] + x.w * w3[3];
        #pragma unroll
        for (int off = 32; off > 0; off >>= 1) {
            s0 += __shfl_xor(s0, off); s1 += __shfl_xor(s1, off);
            s2 += __shfl_xor(s2, off); s3 += __shfl_xor(s3, off);
        }
        if (lane == 0) {
            float4 o = make_float4(s0 + b0, s1 + b1, s2 + b2, s3 + b3);
            *(float4*)(out + (size_t)row * 4) = o;
        }
    }
}

extern "C" void kernel_launch(void* const* d_in, const int* in_sizes, int n_in,
                              void* d_out, int out_size, void* d_ws, size_t ws_size,
                              hipStream_t stream) {
    (void)in_sizes; (void)n_in; (void)out_size; (void)ws_size;
    const float* x_movie    = (const float*)d_in[0];
    const float* x_director = (const float*)d_in[1];
    const float* x_actor    = (const float*)d_in[2];
    const int*   e_dm_src = (const int*)d_in[8];
    const int*   e_dm_dst = (const int*)d_in[9];
    const float* a_dm     = (const float*)d_in[10];
    const float* m_dm     = (const float*)d_in[11];
    const float* p_dm     = (const float*)d_in[12];
    const int*   e_am_src = (const int*)d_in[18];
    const int*   e_am_dst = (const int*)d_in[19];
    const float* a_am     = (const float*)d_in[20];
    const float* m_am     = (const float*)d_in[21];
    const float* p_am     = (const float*)d_in[22];
    const float* W_in_m = (const float*)d_in[23];
    const float* b_in_m = (const float*)d_in[24];
    const float* Wq_m   = (const float*)d_in[27];
    const float* bq_m   = (const float*)d_in[28];
    const float* Wa_m   = (const float*)d_in[31];
    const float* ba_m   = (const float*)d_in[32];
    const float* skip_m = (const float*)d_in[33];
    const float* W_in_d = (const float*)d_in[34];
    const float* b_in_d = (const float*)d_in[35];
    const float* Wk_d   = (const float*)d_in[36];
    const float* bk_d   = (const float*)d_in[37];
    const float* Wv_d   = (const float*)d_in[40];
    const float* bv_d   = (const float*)d_in[41];
    const float* W_in_a = (const float*)d_in[45];
    const float* b_in_a = (const float*)d_in[46];
    const float* Wk_a   = (const float*)d_in[47];
    const float* bk_a   = (const float*)d_in[48];
    const float* Wv_a   = (const float*)d_in[51];
    const float* bv_a   = (const float*)d_in[52];
    const float* W_out  = (const float*)d_in[56];
    const float* b_out  = (const float*)d_in[57];

    // ---- workspace layout ----
    float* ws = (float*)d_ws;
    size_t off = 0;
    float* h_m   = ws + off; off += (size_t)NM * HID;
    float* h_d   = ws + off; off += (size_t)ND * HID;
    float* h_a   = ws + off; off += (size_t)NA * HID;
    float* q_m   = ws + off; off += (size_t)NM * HID;   // reused as out_movie
    float* kt_dm = ws + off; off += (size_t)ND * HID;
    float* vt_dm = ws + off; off += (size_t)ND * HID;
    float* kt_am = ws + off; off += (size_t)NA * HID;
    float* vt_am = ws + off; off += (size_t)NA * HID;
    float* Wf    = ws + off; off += 4 * (size_t)HID * HID;
    float* bf    = ws + off; off += 4 * (size_t)HID;
    float* al    = ws + off; off += (size_t)(E_DM + E_AM) * HEADS;
    int*   amax  = (int*)(ws + off); off += (size_t)NM * HEADS;
    float* den   = ws + off; off += (size_t)NM * HEADS;
    float* num   = ws + off; off += (size_t)NM * HID;
    unsigned short* bt = (unsigned short*)(ws + off);
    unsigned short* Bt_in_m = bt;                 // 256x1024
    unsigned short* Bt_in_d = Bt_in_m + 256 * 1024;
    unsigned short* Bt_in_a = Bt_in_d + 256 * 1024;
    unsigned short* Bt_q_m  = Bt_in_a + 256 * 1024;   // 256x256 each below
    unsigned short* Bt_k_dm = Bt_q_m  + 256 * 256;
    unsigned short* Bt_v_dm = Bt_k_dm + 256 * 256;
    unsigned short* Bt_k_am = Bt_v_dm + 256 * 256;
    unsigned short* Bt_v_am = Bt_k_am + 256 * 256;
    unsigned short* Bt_a_m  = Bt_v_am + 256 * 256;

    float* Wf_k_dm = Wf + 0 * HID * HID;  float* bf_k_dm = bf + 0 * HID;
    float* Wf_v_dm = Wf + 1 * HID * HID;  float* bf_v_dm = bf + 1 * HID;
    float* Wf_k_am = Wf + 2 * HID * HID;  float* bf_k_am = bf + 2 * HID;
    float* Wf_v_am = Wf + 3 * HID * HID;  float* bf_v_am = bf + 3 * HID;

    // fold relation matrices into K/V weights
    fold_w<<<257, 256, 0, stream>>>(Wk_d, bk_d, a_dm, Wf_k_dm, bf_k_dm);
    fold_w<<<257, 256, 0, stream>>>(Wv_d, bv_d, m_dm, Wf_v_dm, bf_v_dm);
    fold_w<<<257, 256, 0, stream>>>(Wk_a, bk_a, a_am, Wf_k_am, bf_k_am);
    fold_w<<<257, 256, 0, stream>>>(Wv_a, bv_a, m_am, Wf_v_am, bf_v_am);

    // transpose+convert all GEMM B-matrices to bf16 [256][K]
    dim3 gK(FIN / 32, 8), gH(HID / 32, 8);
    wt_prep<<<gK, 256, 0, stream>>>(W_in_m, Bt_in_m, FIN);
    wt_prep<<<gK, 256, 0, stream>>>(W_in_d, Bt_in_d, FIN);
    wt_prep<<<gK, 256, 0, stream>>>(W_in_a, Bt_in_a, FIN);
    wt_prep<<<gH, 256, 0, stream>>>(Wq_m,    Bt_q_m,  HID);
    wt_prep<<<gH, 256, 0, stream>>>(Wf_k_dm, Bt_k_dm, HID);
    wt_prep<<<gH, 256, 0, stream>>>(Wf_v_dm, Bt_v_dm, HID);
    wt_prep<<<gH, 256, 0, stream>>>(Wf_k_am, Bt_k_am, HID);
    wt_prep<<<gH, 256, 0, stream>>>(Wf_v_am, Bt_v_am, HID);
    wt_prep<<<gH, 256, 0, stream>>>(Wa_m,    Bt_a_m,  HID);

    int bm_m = (NM + GBM - 1) / GBM;  // 391
    int bm_d = (ND + GBM - 1) / GBM;  // 79
    int bm_a = (NA + GBM - 1) / GBM;  // 196

    // launch (a): input projections, K=1024, 3 descs in one grid
    {
        GMulti mu{};
        mu.nd = 3;
        mu.d[0] = {x_movie,    Bt_in_m, b_in_m, h_m, nullptr, nullptr, NM, FIN, 0, 0};
        mu.d[1] = {x_director, Bt_in_d, b_in_d, h_d, nullptr, nullptr, ND, FIN, 0, bm_m};
        mu.d[2] = {x_actor,    Bt_in_a, b_in_a, h_a, nullptr, nullptr, NA, FIN, 0, bm_m + bm_d};
        gemm_mfma<<<bm_m + bm_d + bm_a, 512, 0, stream>>>(mu);
    }
    // launch (b): q/k/v projections, K=256, 5 descs
    {
        GMulti mu{};
        mu.nd = 5;
        int b0 = 0;
        mu.d[0] = {h_m, Bt_q_m,  bq_m,    q_m,   nullptr, nullptr, NM, HID, 0, b0}; b0 += bm_m;
        mu.d[1] = {h_d, Bt_k_dm, bf_k_dm, kt_dm, nullptr, nullptr, ND, HID, 0, b0}; b0 += bm_d;
        mu.d[2] = {h_d, Bt_v_dm, bf_v_dm, vt_dm, nullptr, nullptr, ND, HID, 0, b0}; b0 += bm_d;
        mu.d[3] = {h_a, Bt_k_am, bf_k_am, kt_am, nullptr, nullptr, NA, HID, 0, b0}; b0 += bm_a;
        mu.d[4] = {h_a, Bt_v_am, bf_v_am, vt_am, nullptr, nullptr, NA, HID, 0, b0}; b0 += bm_a;
        gemm_mfma<<<b0, 512, 0, stream>>>(mu);
    }

    // init accumulators (re-init every call)
    hipMemsetAsync(den, 0, (size_t)NM * HEADS * sizeof(float), stream);
    hipMemsetAsync(num, 0, (size_t)NM * HID * sizeof(float), stream);
    init_amax<<<(NM * HEADS + 255) / 256, 256, 0, stream>>>(amax, NM * HEADS);

    // edge passes
    edge_score<<<(E_DM + EPB - 1) / EPB, 256, 0, stream>>>(e_dm_src, e_dm_dst, kt_dm, q_m, p_dm, al, amax, E_DM);
    edge_score<<<(E_AM + EPB - 1) / EPB, 256, 0, stream>>>(e_am_src, e_am_dst, kt_am, q_m, p_am,
                                                           al + (size_t)E_DM * HEADS, amax, E_AM);
    edge_scatter<<<(E_DM + EPB - 1) / EPB, 256, 0, stream>>>(e_dm_src, e_dm_dst, vt_dm, al, amax, num, den, E_DM);
    edge_scatter<<<(E_AM + EPB - 1) / EPB, 256, 0, stream>>>(e_am_src, e_am_dst, vt_am,
                                                             al + (size_t)E_DM * HEADS, amax, num, den, E_AM);
    finalize_agg<<<(NM * HID + 255) / 256, 256, 0, stream>>>(num, den, NM);

    // launch (c): out_movie = beta*gelu(agg@Wa+ba)+(1-beta)*h_m  (into q_m)
    {
        GMulti mu{};
        mu.nd = 1;
        mu.d[0] = {num, Bt_a_m, ba_m, q_m, h_m, skip_m, NM, HID, 1, 0};
        gemm_mfma<<<bm_m, 512, 0, stream>>>(mu);
    }

    // classifier
    classifier<<<256, 256, 0, stream>>>(q_m, W_out, b_out, (float*)d_out, NM);
}

// Round 3
// 530.670 us; speedup vs baseline: 5.5721x; 1.8893x over previous
//
#include <hip/hip_runtime.h>
#include <math.h>

// ---- problem constants ----
#define NM 50000
#define ND 10000
#define NA 25000
#define E_DM 150000
#define E_AM 300000
#define E_TOT (E_DM + E_AM)
#define HID 256
#define HEADS 8
#define HD 32
#define FIN 1024
#define SCALE 0.17677669529663687f  // 1/sqrt(32)

typedef __attribute__((ext_vector_type(8))) short short8;
typedef __attribute__((ext_vector_type(4))) float f32x4;

// RNE f32 -> bf16 (packed pair into one u32)
__device__ __forceinline__ unsigned int pk_bf16(float x, float y) {
    unsigned int a = __float_as_uint(x), b = __float_as_uint(y);
    a += 0x7FFFu + ((a >> 16) & 1u);
    b += 0x7FFFu + ((b >> 16) & 1u);
    return (a >> 16) | (b & 0xFFFF0000u);
}
__device__ __forceinline__ unsigned short to_bf16(float x) {
    unsigned int a = __float_as_uint(x);
    a += 0x7FFFu + ((a >> 16) & 1u);
    return (unsigned short)(a >> 16);
}

// Fold per-head relation matrix a[8][32][32] into W[256][256] (and bias).
__global__ void fold_w(const float* __restrict__ W, const float* __restrict__ b,
                       const float* __restrict__ a, float* __restrict__ Wf,
                       float* __restrict__ bf) {
    int c = threadIdx.x;            // 0..255
    int h = c >> 5, f = c & 31;
    int r = blockIdx.x;             // 0..256
    float acc = 0.f;
    if (r < HID) {
        #pragma unroll
        for (int d = 0; d < HD; ++d)
            acc += W[r * HID + h * HD + d] * a[(h * HD + d) * HD + f];
        Wf[r * HID + c] = acc;
    } else {
        #pragma unroll
        for (int d = 0; d < HD; ++d)
            acc += b[h * HD + d] * a[(h * HD + d) * HD + f];
        bf[c] = acc;
    }
}

// Transpose + convert weight fp32 [K][256] -> bf16 Bt [256][K]
__global__ void wt_prep(const float* __restrict__ W, unsigned short* __restrict__ Bt, int K) {
    __shared__ float tile[32][33];
    int k0 = blockIdx.x * 32;
    int c0 = blockIdx.y * 32;
    int t = threadIdx.x;            // 256
    int r = t >> 5, c = t & 31;
    #pragma unroll
    for (int rr = 0; rr < 32; rr += 8)
        tile[r + rr][c] = W[(size_t)(k0 + r + rr) * HID + c0 + c];
    __syncthreads();
    #pragma unroll
    for (int rr = 0; rr < 32; rr += 8) {
        int row = r + rr;           // output row (= W column)
        Bt[(size_t)(c0 + row) * K + k0 + c] = to_bf16(tile[c][row]);
    }
}

// ---- multi-descriptor MFMA GEMM: C[M,256] = A[M,K] @ B[K,256] + bias ----
struct GDesc {
    const float* A; const unsigned short* Bt; const float* bias; float* C;
    const float* hskip; const float* gate; int M; int K; int epi; int b0;
};
struct GMulti { GDesc d[5]; int nd; };

#define GBM 128
#define LDP 40   // padded row length in bf16 elems (32 + 8)

__launch_bounds__(512)
__global__ void gemm_mfma(GMulti mu) {
    __shared__ unsigned short sA[GBM * LDP];   // 10240 B
    __shared__ unsigned short sB[HID * LDP];   // 20480 B

    int bid = blockIdx.x;
    int di = 0;
    #pragma unroll
    for (int i = 1; i < 5; ++i)
        if (i < mu.nd && bid >= mu.d[i].b0) di = i;
    GDesc g = mu.d[di];
    int bm = (bid - g.b0) * GBM;
    int M = g.M, K = g.K;

    int t = threadIdx.x;
    int lane = t & 63;
    int wid = t >> 6;               // 0..7
    int wr = wid >> 2;              // 0..1
    int wc = wid & 3;               // 0..3
    int l16 = lane & 15;
    int lk = (lane >> 4) * 8;       // frag k offset: 0,8,16,24

    int arow = t >> 2;              // 0..127
    int aseg = (t & 3) * 8;         // 0,8,16,24
    const float* Ap = (bm + arow < M) ? (g.A + (size_t)(bm + arow) * K + aseg) : nullptr;

    f32x4 acc[4][4];
    #pragma unroll
    for (int m = 0; m < 4; ++m)
        #pragma unroll
        for (int n = 0; n < 4; ++n) acc[m][n] = (f32x4)(0.f);

    for (int k0 = 0; k0 < K; k0 += 32) {
        unsigned int u0 = 0, u1 = 0, u2 = 0, u3 = 0;
        if (Ap) {
            float4 a0 = *(const float4*)(Ap + k0);
            float4 a1 = *(const float4*)(Ap + k0 + 4);
            u0 = pk_bf16(a0.x, a0.y); u1 = pk_bf16(a0.z, a0.w);
            u2 = pk_bf16(a1.x, a1.y); u3 = pk_bf16(a1.z, a1.w);
        }
        *(uint4*)&sA[arow * LDP + aseg] = make_uint4(u0, u1, u2, u3);

        #pragma unroll
        for (int it = 0; it < 2; ++it) {
            int c2 = t + it * 512;          // 0..1023
            int n = c2 >> 2;                // 0..255
            int sg = (c2 & 3) * 8;
            uint4 v = *(const uint4*)(g.Bt + (size_t)n * K + k0 + sg);
            *(uint4*)&sB[n * LDP + sg] = v;
        }
        __syncthreads();

        short8 af[4], bfr[4];
        #pragma unroll
        for (int m = 0; m < 4; ++m)
            af[m] = *(const short8*)&sA[(wr * 64 + m * 16 + l16) * LDP + lk];
        #pragma unroll
        for (int n = 0; n < 4; ++n)
            bfr[n] = *(const short8*)&sB[(wc * 64 + n * 16 + l16) * LDP + lk];
        #pragma unroll
        for (int m = 0; m < 4; ++m)
            #pragma unroll
            for (int n = 0; n < 4; ++n)
                acc[m][n] = __builtin_amdgcn_mfma_f32_16x16x32_bf16(af[m], bfr[n], acc[m][n], 0, 0, 0);
        __syncthreads();
    }

    float beta = 0.f;
    if (g.epi) beta = 1.f / (1.f + expf(-g.gate[0]));
    #pragma unroll
    for (int m = 0; m < 4; ++m) {
        int rb = bm + wr * 64 + m * 16 + (lane >> 4) * 4;
        #pragma unroll
        for (int j = 0; j < 4; ++j) {
            int grow = rb + j;
            if (grow >= M) continue;
            #pragma unroll
            for (int n = 0; n < 4; ++n) {
                int col = wc * 64 + n * 16 + l16;
                float v = acc[m][n][j] + g.bias[col];
                if (g.epi) {
                    float x = v;
                    float gl = 0.5f * x * (1.f + tanhf(0.7978845608028654f * (x + 0.044715f * x * x * x)));
                    v = beta * gl + (1.f - beta) * g.hskip[(size_t)grow * HID + col];
                }
                g.C[(size_t)grow * HID + col] = v;
            }
        }
    }
}

// ---- CSR build ----
__global__ void hist_deg(const int* __restrict__ dA, const int* __restrict__ dB,
                         int* __restrict__ deg) {
    int i = blockIdx.x * 256 + threadIdx.x;
    if (i < E_DM) atomicAdd(&deg[dA[i]], 1);
    else if (i < E_TOT) atomicAdd(&deg[dB[i - E_DM]], 1);
}

__global__ void scan_pass1(const int* __restrict__ deg, int* __restrict__ bsum) {
    __shared__ int s[256];
    int b = blockIdx.x, t = threadIdx.x;
    int i = b * 256 + t;
    int v = (i < NM) ? deg[i] : 0;
    s[t] = v; __syncthreads();
    for (int off = 128; off > 0; off >>= 1) {
        if (t < off) s[t] += s[t + off];
        __syncthreads();
    }
    if (t == 0) bsum[b] = s[0];
}

__global__ void scan_pass2(const int* __restrict__ bsum, int* __restrict__ boff, int nb) {
    __shared__ int s[256];
    int t = threadIdx.x;
    int v = (t < nb) ? bsum[t] : 0;
    s[t] = v; __syncthreads();
    for (int off = 1; off < 256; off <<= 1) {
        int x = (t >= off) ? s[t - off] : 0;
        __syncthreads();
        s[t] += x;
        __syncthreads();
    }
    if (t < nb) boff[t] = s[t] - v;   // exclusive
}

__global__ void scan_pass3(const int* __restrict__ deg, const int* __restrict__ boff,
                           int* __restrict__ rowptr, int* __restrict__ cursor) {
    __shared__ int s[256];
    int b = blockIdx.x, t = threadIdx.x, i = b * 256 + t;
    int v = (i < NM) ? deg[i] : 0;
    s[t] = v; __syncthreads();
    for (int off = 1; off < 256; off <<= 1) {
        int x = (t >= off) ? s[t - off] : 0;
        __syncthreads();
        s[t] += x;
        __syncthreads();
    }
    int excl = s[t] - v + boff[b];
    if (i < NM) { rowptr[i] = excl; cursor[i] = excl; }
    if (i == 0) rowptr[NM] = E_TOT;
}

__global__ void fill_adj(const int* __restrict__ sA, const int* __restrict__ dA,
                         const int* __restrict__ sB, const int* __restrict__ dB,
                         int* __restrict__ cursor, int* __restrict__ adj) {
    int i = blockIdx.x * 256 + threadIdx.x;
    int d, entry;
    if (i < E_DM)      { d = dA[i];        entry = sA[i]; }
    else if (i < E_TOT){ int j = i - E_DM; d = dB[j]; entry = (sB[j] + ND) | (1 << 16); }
    else return;
    int pos = atomicAdd(&cursor[d], 1);
    adj[pos] = entry;
}

// ---- fused per-destination attention aggregation (online softmax) ----
// kt_all/vt_all: rows [0,ND) = director (rel dm), [ND,ND+NA) = actor (rel am)
__launch_bounds__(256)
__global__ void agg_fused(const int* __restrict__ rowptr, const int* __restrict__ adj,
                          const float* __restrict__ q, const float* __restrict__ kt_all,
                          const float* __restrict__ vt_all,
                          const float* __restrict__ p_dm, const float* __restrict__ p_am,
                          float* __restrict__ agg) {
    int d = blockIdx.x;
    int t = threadIdx.x;
    int h = t >> 5;
    int start = rowptr[d], end = rowptr[d + 1];
    float qv = q[(size_t)d * HID + t];
    float pr0 = p_dm[h] * SCALE, pr1 = p_am[h] * SCALE;
    float m = -INFINITY, den = 0.f, acc = 0.f;
    for (int i = start; i < end; ++i) {
        int e = adj[i];
        int sr = e & 0xFFFF;
        float kv = kt_all[(size_t)sr * HID + t];
        float prod = qv * kv;
        #pragma unroll
        for (int off = 16; off > 0; off >>= 1) prod += __shfl_xor(prod, off);
        float a = prod * ((e >> 16) ? pr1 : pr0);
        float mn = fmaxf(m, a);
        float c  = __expf(m - mn);   // first iter: exp(-inf) = 0
        float ex = __expf(a - mn);
        float vv = vt_all[(size_t)sr * HID + t];
        den = den * c + ex;
        acc = acc * c + ex * vv;
        m = mn;
    }
    agg[(size_t)d * HID + t] = (end > start) ? acc / den : 0.f;
}

// out[M,4] = X[M,256] @ W[256,4] + b   — one wave per row, shuffle reduce
__launch_bounds__(256)
__global__ void classifier(const float* __restrict__ X, const float* __restrict__ W,
                           const float* __restrict__ b, float* __restrict__ out, int M) {
    int t = threadIdx.x, lane = t & 63;
    int wid = blockIdx.x * 4 + (t >> 6);
    int nw = gridDim.x * 4;
    float w0[4], w1[4], w2[4], w3[4];
    #pragma unroll
    for (int j = 0; j < 4; ++j) {
        float4 wv = *(const float4*)(W + (lane * 4 + j) * 4);
        w0[j] = wv.x; w1[j] = wv.y; w2[j] = wv.z; w3[j] = wv.w;
    }
    float b0 = b[0], b1 = b[1], b2 = b[2], b3 = b[3];
    for (int row = wid; row < M; row += nw) {
        float4 x = *(const float4*)(X + (size_t)row * HID + lane * 4);
        float s0 = x.x * w0[0] + x.y * w0[1] + x.z * w0[2] + x.w * w0[3];
        float s1 = x.x * w1[0] + x.y * w1[1] + x.z * w1[2] + x.w * w1[3];
        float s2 = x.x * w2[0] + x.y * w2[1] + x.z * w2[2] + x.w * w2[3];
        float s3 = x.x * w3[0] + x.y * w3[1] + x.z * w3[2] + x.w * w3[3];
        #pragma unroll
        for (int off = 32; off > 0; off >>= 1) {
            s0 += __shfl_xor(s0, off); s1 += __shfl_xor(s1, off);
            s2 += __shfl_xor(s2, off); s3 += __shfl_xor(s3, off);
        }
        if (lane == 0) {
            float4 o = make_float4(s0 + b0, s1 + b1, s2 + b2, s3 + b3);
            *(float4*)(out + (size_t)row * 4) = o;
        }
    }
}

extern "C" void kernel_launch(void* const* d_in, const int* in_sizes, int n_in,
                              void* d_out, int out_size, void* d_ws, size_t ws_size,
                              hipStream_t stream) {
    (void)in_sizes; (void)n_in; (void)out_size; (void)ws_size;
    const float* x_movie    = (const float*)d_in[0];
    const float* x_director = (const float*)d_in[1];
    const float* x_actor    = (const float*)d_in[2];
    const int*   e_dm_src = (const int*)d_in[8];
    const int*   e_dm_dst = (const int*)d_in[9];
    const float* a_dm     = (const float*)d_in[10];
    const float* m_dm     = (const float*)d_in[11];
    const float* p_dm     = (const float*)d_in[12];
    const int*   e_am_src = (const int*)d_in[18];
    const int*   e_am_dst = (const int*)d_in[19];
    const float* a_am     = (const float*)d_in[20];
    const float* m_am     = (const float*)d_in[21];
    const float* p_am     = (const float*)d_in[22];
    const float* W_in_m = (const float*)d_in[23];
    const float* b_in_m = (const float*)d_in[24];
    const float* Wq_m   = (const float*)d_in[27];
    const float* bq_m   = (const float*)d_in[28];
    const float* Wa_m   = (const float*)d_in[31];
    const float* ba_m   = (const float*)d_in[32];
    const float* skip_m = (const float*)d_in[33];
    const float* W_in_d = (const float*)d_in[34];
    const float* b_in_d = (const float*)d_in[35];
    const float* Wk_d   = (const float*)d_in[36];
    const float* bk_d   = (const float*)d_in[37];
    const float* Wv_d   = (const float*)d_in[40];
    const float* bv_d   = (const float*)d_in[41];
    const float* W_in_a = (const float*)d_in[45];
    const float* b_in_a = (const float*)d_in[46];
    const float* Wk_a   = (const float*)d_in[47];
    const float* bk_a   = (const float*)d_in[48];
    const float* Wv_a   = (const float*)d_in[51];
    const float* bv_a   = (const float*)d_in[52];
    const float* W_out  = (const float*)d_in[56];
    const float* b_out  = (const float*)d_in[57];

    // ---- workspace layout ----
    float* ws = (float*)d_ws;
    size_t off = 0;
    float* h_m   = ws + off; off += (size_t)NM * HID;
    float* h_d   = ws + off; off += (size_t)ND * HID;
    float* h_a   = ws + off; off += (size_t)NA * HID;
    float* q_m   = ws + off; off += (size_t)NM * HID;   // reused as out_movie
    float* kt_all = ws + off; off += (size_t)(ND + NA) * HID;  // dm rows, then am rows
    float* vt_all = ws + off; off += (size_t)(ND + NA) * HID;
    float* Wf    = ws + off; off += 4 * (size_t)HID * HID;
    float* bf    = ws + off; off += 4 * (size_t)HID;
    float* agg   = ws + off; off += (size_t)NM * HID;
    int* deg     = (int*)(ws + off); off += NM;
    int* rowptr  = (int*)(ws + off); off += NM + 1;
    int* cursor  = (int*)(ws + off); off += NM;
    int* bsum    = (int*)(ws + off); off += 256;
    int* boff    = (int*)(ws + off); off += 256;
    int* adj     = (int*)(ws + off); off += E_TOT;
    unsigned short* bt = (unsigned short*)(ws + off);
    unsigned short* Bt_in_m = bt;
    unsigned short* Bt_in_d = Bt_in_m + 256 * 1024;
    unsigned short* Bt_in_a = Bt_in_d + 256 * 1024;
    unsigned short* Bt_q_m  = Bt_in_a + 256 * 1024;
    unsigned short* Bt_k_dm = Bt_q_m  + 256 * 256;
    unsigned short* Bt_v_dm = Bt_k_dm + 256 * 256;
    unsigned short* Bt_k_am = Bt_v_dm + 256 * 256;
    unsigned short* Bt_v_am = Bt_k_am + 256 * 256;
    unsigned short* Bt_a_m  = Bt_v_am + 256 * 256;

    float* kt_dm = kt_all;
    float* kt_am = kt_all + (size_t)ND * HID;
    float* vt_dm = vt_all;
    float* vt_am = vt_all + (size_t)ND * HID;

    float* Wf_k_dm = Wf + 0 * HID * HID;  float* bf_k_dm = bf + 0 * HID;
    float* Wf_v_dm = Wf + 1 * HID * HID;  float* bf_v_dm = bf + 1 * HID;
    float* Wf_k_am = Wf + 2 * HID * HID;  float* bf_k_am = bf + 2 * HID;
    float* Wf_v_am = Wf + 3 * HID * HID;  float* bf_v_am = bf + 3 * HID;

    // ---- CSR build (independent of GEMMs) ----
    hipMemsetAsync(deg, 0, NM * sizeof(int), stream);
    hist_deg<<<(E_TOT + 255) / 256, 256, 0, stream>>>(e_dm_dst, e_am_dst, deg);
    int nb = (NM + 255) / 256;  // 196
    scan_pass1<<<nb, 256, 0, stream>>>(deg, bsum);
    scan_pass2<<<1, 256, 0, stream>>>(bsum, boff, nb);
    scan_pass3<<<nb, 256, 0, stream>>>(deg, boff, rowptr, cursor);
    fill_adj<<<(E_TOT + 255) / 256, 256, 0, stream>>>(e_dm_src, e_dm_dst, e_am_src, e_am_dst,
                                                      cursor, adj);

    // fold relation matrices into K/V weights
    fold_w<<<257, 256, 0, stream>>>(Wk_d, bk_d, a_dm, Wf_k_dm, bf_k_dm);
    fold_w<<<257, 256, 0, stream>>>(Wv_d, bv_d, m_dm, Wf_v_dm, bf_v_dm);
    fold_w<<<257, 256, 0, stream>>>(Wk_a, bk_a, a_am, Wf_k_am, bf_k_am);
    fold_w<<<257, 256, 0, stream>>>(Wv_a, bv_a, m_am, Wf_v_am, bf_v_am);

    // transpose+convert all GEMM B-matrices to bf16 [256][K]
    dim3 gK(FIN / 32, 8), gH(HID / 32, 8);
    wt_prep<<<gK, 256, 0, stream>>>(W_in_m, Bt_in_m, FIN);
    wt_prep<<<gK, 256, 0, stream>>>(W_in_d, Bt_in_d, FIN);
    wt_prep<<<gK, 256, 0, stream>>>(W_in_a, Bt_in_a, FIN);
    wt_prep<<<gH, 256, 0, stream>>>(Wq_m,    Bt_q_m,  HID);
    wt_prep<<<gH, 256, 0, stream>>>(Wf_k_dm, Bt_k_dm, HID);
    wt_prep<<<gH, 256, 0, stream>>>(Wf_v_dm, Bt_v_dm, HID);
    wt_prep<<<gH, 256, 0, stream>>>(Wf_k_am, Bt_k_am, HID);
    wt_prep<<<gH, 256, 0, stream>>>(Wf_v_am, Bt_v_am, HID);
    wt_prep<<<gH, 256, 0, stream>>>(Wa_m,    Bt_a_m,  HID);

    int bm_m = (NM + GBM - 1) / GBM;  // 391
    int bm_d = (ND + GBM - 1) / GBM;  // 79
    int bm_a = (NA + GBM - 1) / GBM;  // 196

    // launch (a): input projections, K=1024
    {
        GMulti mu{};
        mu.nd = 3;
        mu.d[0] = {x_movie,    Bt_in_m, b_in_m, h_m, nullptr, nullptr, NM, FIN, 0, 0};
        mu.d[1] = {x_director, Bt_in_d, b_in_d, h_d, nullptr, nullptr, ND, FIN, 0, bm_m};
        mu.d[2] = {x_actor,    Bt_in_a, b_in_a, h_a, nullptr, nullptr, NA, FIN, 0, bm_m + bm_d};
        gemm_mfma<<<bm_m + bm_d + bm_a, 512, 0, stream>>>(mu);
    }
    // launch (b): q/k/v projections, K=256
    {
        GMulti mu{};
        mu.nd = 5;
        int b0 = 0;
        mu.d[0] = {h_m, Bt_q_m,  bq_m,    q_m,   nullptr, nullptr, NM, HID, 0, b0}; b0 += bm_m;
        mu.d[1] = {h_d, Bt_k_dm, bf_k_dm, kt_dm, nullptr, nullptr, ND, HID, 0, b0}; b0 += bm_d;
        mu.d[2] = {h_d, Bt_v_dm, bf_v_dm, vt_dm, nullptr, nullptr, ND, HID, 0, b0}; b0 += bm_d;
        mu.d[3] = {h_a, Bt_k_am, bf_k_am, kt_am, nullptr, nullptr, NA, HID, 0, b0}; b0 += bm_a;
        mu.d[4] = {h_a, Bt_v_am, bf_v_am, vt_am, nullptr, nullptr, NA, HID, 0, b0}; b0 += bm_a;
        gemm_mfma<<<b0, 512, 0, stream>>>(mu);
    }

    // fused per-destination aggregation (replaces score/scatter/finalize)
    agg_fused<<<NM, 256, 0, stream>>>(rowptr, adj, q_m, kt_all, vt_all, p_dm, p_am, agg);

    // launch (c): out_movie = beta*gelu(agg@Wa+ba)+(1-beta)*h_m  (into q_m)
    {
        GMulti mu{};
        mu.nd = 1;
        mu.d[0] = {agg, Bt_a_m, ba_m, q_m, h_m, skip_m, NM, HID, 1, 0};
        gemm_mfma<<<bm_m, 512, 0, stream>>>(mu);
    }

    // classifier
    classifier<<<256, 256, 0, stream>>>(q_m, W_out, b_out, (float*)d_out, NM);
}

// Round 4
// 490.290 us; speedup vs baseline: 6.0310x; 1.0824x over previous
//
#include <hip/hip_runtime.h>
#include <math.h>

// ---- problem constants ----
#define NM 50000
#define ND 10000
#define NA 25000
#define E_DM 150000
#define E_AM 300000
#define E_TOT (E_DM + E_AM)
#define HID 256
#define HEADS 8
#define HD 32
#define FIN 1024
#define SCALE 0.17677669529663687f  // 1/sqrt(32)

typedef __attribute__((ext_vector_type(8))) short short8;
typedef __attribute__((ext_vector_type(4))) float f32x4;

typedef __attribute__((address_space(1))) const unsigned char gas_u8;
typedef __attribute__((address_space(3))) unsigned char las_u8;

// async global->LDS 16B: global per-lane address, LDS wave-uniform base (+lane*16 by HW)
__device__ __forceinline__ void gload16(const void* g, void* l) {
    gas_u8* gp = (gas_u8*)(unsigned long long)(uintptr_t)g;
    las_u8* lp = (las_u8*)(unsigned int)(uintptr_t)l;  // generic LDS ptr: low 32b = LDS offset
    __builtin_amdgcn_global_load_lds((const __attribute__((address_space(1))) void*)gp,
                                     (__attribute__((address_space(3))) void*)lp, 16, 0, 0);
}

// RNE f32 -> bf16
__device__ __forceinline__ unsigned int pk_bf16(float x, float y) {
    unsigned int a = __float_as_uint(x), b = __float_as_uint(y);
    a += 0x7FFFu + ((a >> 16) & 1u);
    b += 0x7FFFu + ((b >> 16) & 1u);
    return (a >> 16) | (b & 0xFFFF0000u);
}
__device__ __forceinline__ unsigned short to_bf16(float x) {
    unsigned int a = __float_as_uint(x);
    a += 0x7FFFu + ((a >> 16) & 1u);
    return (unsigned short)(a >> 16);
}
__device__ __forceinline__ float bf2f(unsigned short u) {
    return __uint_as_float(((unsigned int)u) << 16);
}

// ---- fold per-head relation matrix into W (4 descs in one launch) ----
struct F4 { const float* W[4]; const float* b[4]; const float* a[4]; float* Wf[4]; float* bf[4]; };
__global__ void fold_w4(F4 f4) {
    int di = blockIdx.y;
    const float* W = f4.W[di]; const float* b = f4.b[di]; const float* a = f4.a[di];
    float* Wf = f4.Wf[di]; float* bf = f4.bf[di];
    int c = threadIdx.x;            // 0..255
    int h = c >> 5, f = c & 31;
    int r = blockIdx.x;             // 0..256
    float acc = 0.f;
    if (r < HID) {
        #pragma unroll
        for (int d = 0; d < HD; ++d)
            acc += W[r * HID + h * HD + d] * a[(h * HD + d) * HD + f];
        Wf[r * HID + c] = acc;
    } else {
        #pragma unroll
        for (int d = 0; d < HD; ++d)
            acc += b[h * HD + d] * a[(h * HD + d) * HD + f];
        bf[c] = acc;
    }
}

// ---- pack W fp32 [K][256] -> bf16 fragment order [K/32][16 subtile][64 lane][8] ----
struct PDesc { const float* W; unsigned short* out; int K; int b0; };
struct PMulti { PDesc d[9]; int nd; };
__global__ void wt_pack(PMulti pm) {
    int bid = blockIdx.x; int di = 0;
    #pragma unroll
    for (int i = 1; i < 9; ++i) if (i < pm.nd && bid >= pm.d[i].b0) di = i;
    PDesc p = pm.d[di];
    int kstep = bid - p.b0;
    int t = threadIdx.x;
    #pragma unroll
    for (int i = 0; i < 32; ++i) {
        int idx = i * 256 + t;
        int n0 = idx >> 9, r = idx & 511, lane = r >> 3, j = r & 7;
        int k = kstep * 32 + (lane >> 4) * 8 + j;
        int c = n0 * 16 + (lane & 15);
        p.out[(size_t)kstep * 8192 + idx] = to_bf16(p.W[(size_t)k * HID + c]);
    }
}

// ---- multi-descriptor MFMA GEMM: C[M,256] = A[M,K]@B + bias ----
// Bt fragment-packed bf16; A fp32 converted during staging. Double-buffered,
// one barrier per K-step; B staged via global_load_lds; all LDS linear lane*16.
struct GDesc {
    const float* A; const unsigned short* Bt; const float* bias; float* C;
    const float* hskip; const float* gate; int M; int K; int epi; int obf; int b0;
};
struct GMulti { GDesc d[5]; int nd; };

#define GBM 128

__launch_bounds__(512, 4)
__global__ void gemm_mfma(GMulti mu) {
    __shared__ unsigned short sB[2][16 * 512];   // 32 KB
    __shared__ unsigned short sA[2][8 * 512];    // 16 KB

    int bid = blockIdx.x;
    int di = 0;
    #pragma unroll
    for (int i = 1; i < 5; ++i)
        if (i < mu.nd && bid >= mu.d[i].b0) di = i;
    GDesc g = mu.d[di];
    int bm = (bid - g.b0) * GBM;
    int M = g.M, K = g.K;

    int t = threadIdx.x;
    int lane = t & 63;
    int w = t >> 6;                 // 0..7
    int wr = w >> 2, wc = w & 3;
    int l16 = lane & 15;

    // A staging: thread t stages subtile m0=t>>6, lane's fragment slot
    int arow = bm + (t >> 6) * 16 + (t & 15);
    const float* Ap = (arow < M) ? g.A + (size_t)arow * K + ((lane >> 4) * 8) : nullptr;
    int aoff = (t >> 6) * 512 + lane * 8;

    f32x4 acc[4][4];
    #pragma unroll
    for (int m = 0; m < 4; ++m)
        #pragma unroll
        for (int n = 0; n < 4; ++n) acc[m][n] = (f32x4)(0.f);

    int nk = K >> 5;
    // prologue: stage step 0 into buf 0
    {
        const unsigned short* gB = g.Bt;
        gload16(gB + w * 512 + lane * 8, &sB[0][w * 512]);
        gload16(gB + (w + 8) * 512 + lane * 8, &sB[0][(w + 8) * 512]);
        uint4 pk = make_uint4(0u, 0u, 0u, 0u);
        if (Ap) {
            float4 f0 = *(const float4*)(Ap + 0);
            float4 f1 = *(const float4*)(Ap + 4);
            pk = make_uint4(pk_bf16(f0.x, f0.y), pk_bf16(f0.z, f0.w),
                            pk_bf16(f1.x, f1.y), pk_bf16(f1.z, f1.w));
        }
        *(uint4*)&sA[0][aoff] = pk;
    }
    __syncthreads();

    int cur = 0;
    for (int ks = 0; ks < nk; ++ks) {
        int nxt = cur ^ 1;
        bool pf = (ks + 1 < nk);
        float4 f0, f1;
        if (pf) {
            const unsigned short* gB = g.Bt + (size_t)(ks + 1) * 8192;
            gload16(gB + w * 512 + lane * 8, &sB[nxt][w * 512]);
            gload16(gB + (w + 8) * 512 + lane * 8, &sB[nxt][(w + 8) * 512]);
            if (Ap) {
                f0 = *(const float4*)(Ap + (ks + 1) * 32);
                f1 = *(const float4*)(Ap + (ks + 1) * 32 + 4);
            }
        }
        short8 bfr[4];
        #pragma unroll
        for (int n = 0; n < 4; ++n)
            bfr[n] = *(const short8*)&sB[cur][(wc * 4 + n) * 512 + lane * 8];
        #pragma unroll
        for (int m = 0; m < 4; ++m) {
            short8 af = *(const short8*)&sA[cur][(wr * 4 + m) * 512 + lane * 8];
            #pragma unroll
            for (int n = 0; n < 4; ++n)
                acc[m][n] = __builtin_amdgcn_mfma_f32_16x16x32_bf16(af, bfr[n], acc[m][n], 0, 0, 0);
        }
        if (pf) {
            uint4 pk = make_uint4(0u, 0u, 0u, 0u);
            if (Ap) pk = make_uint4(pk_bf16(f0.x, f0.y), pk_bf16(f0.z, f0.w),
                                    pk_bf16(f1.x, f1.y), pk_bf16(f1.z, f1.w));
            *(uint4*)&sA[nxt][aoff] = pk;
        }
        __syncthreads();
        cur = nxt;
    }

    float beta = 0.f;
    if (g.epi) beta = 1.f / (1.f + expf(-g.gate[0]));
    #pragma unroll
    for (int m = 0; m < 4; ++m) {
        int rb = bm + wr * 64 + m * 16 + (lane >> 4) * 4;
        #pragma unroll
        for (int j = 0; j < 4; ++j) {
            int grow = rb + j;
            if (grow >= M) continue;
            #pragma unroll
            for (int n = 0; n < 4; ++n) {
                int col = wc * 64 + n * 16 + l16;
                float v = acc[m][n][j] + g.bias[col];
                if (g.epi) {
                    float x = v;
                    float gl = 0.5f * x * (1.f + tanhf(0.7978845608028654f * (x + 0.044715f * x * x * x)));
                    v = beta * gl + (1.f - beta) * g.hskip[(size_t)grow * HID + col];
                }
                if (g.obf) ((unsigned short*)g.C)[(size_t)grow * HID + col] = to_bf16(v);
                else g.C[(size_t)grow * HID + col] = v;
            }
        }
    }
}

// ---- CSR build ----
__global__ void hist_deg(const int* __restrict__ dA, const int* __restrict__ dB,
                         int* __restrict__ deg) {
    int i = blockIdx.x * 256 + threadIdx.x;
    if (i < E_DM) atomicAdd(&deg[dA[i]], 1);
    else if (i < E_TOT) atomicAdd(&deg[dB[i - E_DM]], 1);
}

__global__ void scan_pass1(const int* __restrict__ deg, int* __restrict__ bsum) {
    __shared__ int s[256];
    int b = blockIdx.x, t = threadIdx.x;
    int i = b * 256 + t;
    int v = (i < NM) ? deg[i] : 0;
    s[t] = v; __syncthreads();
    for (int off = 128; off > 0; off >>= 1) {
        if (t < off) s[t] += s[t + off];
        __syncthreads();
    }
    if (t == 0) bsum[b] = s[0];
}

__global__ void scan_pass2(const int* __restrict__ bsum, int* __restrict__ boff, int nb) {
    __shared__ int s[256];
    int t = threadIdx.x;
    int v = (t < nb) ? bsum[t] : 0;
    s[t] = v; __syncthreads();
    for (int off = 1; off < 256; off <<= 1) {
        int x = (t >= off) ? s[t - off] : 0;
        __syncthreads();
        s[t] += x;
        __syncthreads();
    }
    if (t < nb) boff[t] = s[t] - v;   // exclusive
}

__global__ void scan_pass3(const int* __restrict__ deg, const int* __restrict__ boff,
                           int* __restrict__ rowptr, int* __restrict__ cursor) {
    __shared__ int s[256];
    int b = blockIdx.x, t = threadIdx.x, i = b * 256 + t;
    int v = (i < NM) ? deg[i] : 0;
    s[t] = v; __syncthreads();
    for (int off = 1; off < 256; off <<= 1) {
        int x = (t >= off) ? s[t - off] : 0;
        __syncthreads();
        s[t] += x;
        __syncthreads();
    }
    int excl = s[t] - v + boff[b];
    if (i < NM) { rowptr[i] = excl; cursor[i] = excl; }
    if (i == 0) rowptr[NM] = E_TOT;
}

__global__ void fill_adj(const int* __restrict__ sA, const int* __restrict__ dA,
                         const int* __restrict__ sB, const int* __restrict__ dB,
                         int* __restrict__ cursor, int* __restrict__ adj) {
    int i = blockIdx.x * 256 + threadIdx.x;
    int d, entry;
    if (i < E_DM)      { d = dA[i];        entry = sA[i]; }
    else if (i < E_TOT){ int j = i - E_DM; d = dB[j]; entry = (sB[j] + ND) | (1 << 16); }
    else return;
    int pos = atomicAdd(&cursor[d], 1);
    adj[pos] = entry;
}

// ---- fused per-destination attention aggregation (online softmax, bf16 k/v) ----
__launch_bounds__(256)
__global__ void agg_fused(const int* __restrict__ rowptr, const int* __restrict__ adj,
                          const float* __restrict__ q, const unsigned short* __restrict__ kt_all,
                          const unsigned short* __restrict__ vt_all,
                          const float* __restrict__ p_dm, const float* __restrict__ p_am,
                          float* __restrict__ agg) {
    int d = blockIdx.x;
    int t = threadIdx.x;
    int h = t >> 5;
    int start = rowptr[d], end = rowptr[d + 1];
    float qv = q[(size_t)d * HID + t];
    float pr0 = p_dm[h] * SCALE, pr1 = p_am[h] * SCALE;
    float m = -INFINITY, den = 0.f, acc = 0.f;
    for (int i = start; i < end; ++i) {
        int e = adj[i];
        int sr = e & 0xFFFF;
        float kv = bf2f(kt_all[(size_t)sr * HID + t]);
        float prod = qv * kv;
        #pragma unroll
        for (int off = 16; off > 0; off >>= 1) prod += __shfl_xor(prod, off);
        float a = prod * ((e >> 16) ? pr1 : pr0);
        float mn = fmaxf(m, a);
        float c  = __expf(m - mn);
        float ex = __expf(a - mn);
        float vv = bf2f(vt_all[(size_t)sr * HID + t]);
        den = den * c + ex;
        acc = acc * c + ex * vv;
        m = mn;
    }
    agg[(size_t)d * HID + t] = (end > start) ? acc / den : 0.f;
}

// out[M,4] = X[M,256] @ W[256,4] + b
__launch_bounds__(256)
__global__ void classifier(const float* __restrict__ X, const float* __restrict__ W,
                           const float* __restrict__ b, float* __restrict__ out, int M) {
    int t = threadIdx.x, lane = t & 63;
    int wid = blockIdx.x * 4 + (t >> 6);
    int nw = gridDim.x * 4;
    float w0[4], w1[4], w2[4], w3[4];
    #pragma unroll
    for (int j = 0; j < 4; ++j) {
        float4 wv = *(const float4*)(W + (lane * 4 + j) * 4);
        w0[j] = wv.x; w1[j] = wv.y; w2[j] = wv.z; w3[j] = wv.w;
    }
    float b0 = b[0], b1 = b[1], b2 = b[2], b3 = b[3];
    for (int row = wid; row < M; row += nw) {
        float4 x = *(const float4*)(X + (size_t)row * HID + lane * 4);
        float s0 = x.x * w0[0] + x.y * w0[1] + x.z * w0[2] + x.w * w0[3];
        float s1 = x.x * w1[0] + x.y * w1[1] + x.z * w1[2] + x.w * w1[3];
        float s2 = x.x * w2[0] + x.y * w2[1] + x.z * w2[2] + x.w * w2[3];
        float s3 = x.x * w3[0] + x.y * w3[1] + x.z * w3[2] + x.w * w3[3];
        #pragma unroll
        for (int off = 32; off > 0; off >>= 1) {
            s0 += __shfl_xor(s0, off); s1 += __shfl_xor(s1, off);
            s2 += __shfl_xor(s2, off); s3 += __shfl_xor(s3, off);
        }
        if (lane == 0) {
            float4 o = make_float4(s0 + b0, s1 + b1, s2 + b2, s3 + b3);
            *(float4*)(out + (size_t)row * 4) = o;
        }
    }
}

extern "C" void kernel_launch(void* const* d_in, const int* in_sizes, int n_in,
                              void* d_out, int out_size, void* d_ws, size_t ws_size,
                              hipStream_t stream) {
    (void)in_sizes; (void)n_in; (void)out_size; (void)ws_size;
    const float* x_movie    = (const float*)d_in[0];
    const float* x_director = (const float*)d_in[1];
    const float* x_actor    = (const float*)d_in[2];
    const int*   e_dm_src = (const int*)d_in[8];
    const int*   e_dm_dst = (const int*)d_in[9];
    const float* a_dm     = (const float*)d_in[10];
    const float* m_dm     = (const float*)d_in[11];
    const float* p_dm     = (const float*)d_in[12];
    const int*   e_am_src = (const int*)d_in[18];
    const int*   e_am_dst = (const int*)d_in[19];
    const float* a_am     = (const float*)d_in[20];
    const float* m_am     = (const float*)d_in[21];
    const float* p_am     = (const float*)d_in[22];
    const float* W_in_m = (const float*)d_in[23];
    const float* b_in_m = (const float*)d_in[24];
    const float* Wq_m   = (const float*)d_in[27];
    const float* bq_m   = (const float*)d_in[28];
    const float* Wa_m   = (const float*)d_in[31];
    const float* ba_m   = (const float*)d_in[32];
    const float* skip_m = (const float*)d_in[33];
    const float* W_in_d = (const float*)d_in[34];
    const float* b_in_d = (const float*)d_in[35];
    const float* Wk_d   = (const float*)d_in[36];
    const float* bk_d   = (const float*)d_in[37];
    const float* Wv_d   = (const float*)d_in[40];
    const float* bv_d   = (const float*)d_in[41];
    const float* W_in_a = (const float*)d_in[45];
    const float* b_in_a = (const float*)d_in[46];
    const float* Wk_a   = (const float*)d_in[47];
    const float* bk_a   = (const float*)d_in[48];
    const float* Wv_a   = (const float*)d_in[51];
    const float* bv_a   = (const float*)d_in[52];
    const float* W_out  = (const float*)d_in[56];
    const float* b_out  = (const float*)d_in[57];

    // ---- workspace layout (byte cursor, 256B aligned) ----
    char* base = (char*)d_ws;
    size_t off = 0;
    auto alloc = [&](size_t bytes) -> void* {
        void* p = base + off;
        off = (off + bytes + 255) & ~(size_t)255;
        return p;
    };
    float* h_m    = (float*)alloc((size_t)NM * HID * 4);
    float* h_d    = (float*)alloc((size_t)ND * HID * 4);
    float* h_a    = (float*)alloc((size_t)NA * HID * 4);
    float* q_m    = (float*)alloc((size_t)NM * HID * 4);   // reused as out_movie
    float* agg    = (float*)alloc((size_t)NM * HID * 4);
    unsigned short* kt_all = (unsigned short*)alloc((size_t)(ND + NA) * HID * 2);
    unsigned short* vt_all = (unsigned short*)alloc((size_t)(ND + NA) * HID * 2);
    float* Wf     = (float*)alloc(4 * (size_t)HID * HID * 4);
    float* bf     = (float*)alloc(4 * (size_t)HID * 4);
    int* deg      = (int*)alloc(NM * 4);
    int* rowptr   = (int*)alloc((NM + 1) * 4);
    int* cursor   = (int*)alloc(NM * 4);
    int* bsum     = (int*)alloc(256 * 4);
    int* boff     = (int*)alloc(256 * 4);
    int* adj      = (int*)alloc((size_t)E_TOT * 4);
    unsigned short* Bt_in_m = (unsigned short*)alloc((size_t)256 * 1024 * 2);
    unsigned short* Bt_in_d = (unsigned short*)alloc((size_t)256 * 1024 * 2);
    unsigned short* Bt_in_a = (unsigned short*)alloc((size_t)256 * 1024 * 2);
    unsigned short* Bt_q_m  = (unsigned short*)alloc((size_t)256 * 256 * 2);
    unsigned short* Bt_k_dm = (unsigned short*)alloc((size_t)256 * 256 * 2);
    unsigned short* Bt_v_dm = (unsigned short*)alloc((size_t)256 * 256 * 2);
    unsigned short* Bt_k_am = (unsigned short*)alloc((size_t)256 * 256 * 2);
    unsigned short* Bt_v_am = (unsigned short*)alloc((size_t)256 * 256 * 2);
    unsigned short* Bt_a_m  = (unsigned short*)alloc((size_t)256 * 256 * 2);

    unsigned short* kt_dm = kt_all;
    unsigned short* kt_am = kt_all + (size_t)ND * HID;
    unsigned short* vt_dm = vt_all;
    unsigned short* vt_am = vt_all + (size_t)ND * HID;

    float* Wf_k_dm = Wf + 0 * HID * HID;  float* bf_k_dm = bf + 0 * HID;
    float* Wf_v_dm = Wf + 1 * HID * HID;  float* bf_v_dm = bf + 1 * HID;
    float* Wf_k_am = Wf + 2 * HID * HID;  float* bf_k_am = bf + 2 * HID;
    float* Wf_v_am = Wf + 3 * HID * HID;  float* bf_v_am = bf + 3 * HID;

    // ---- CSR build ----
    hipMemsetAsync(deg, 0, NM * sizeof(int), stream);
    hist_deg<<<(E_TOT + 255) / 256, 256, 0, stream>>>(e_dm_dst, e_am_dst, deg);
    int nb = (NM + 255) / 256;  // 196
    scan_pass1<<<nb, 256, 0, stream>>>(deg, bsum);
    scan_pass2<<<1, 256, 0, stream>>>(bsum, boff, nb);
    scan_pass3<<<nb, 256, 0, stream>>>(deg, boff, rowptr, cursor);
    fill_adj<<<(E_TOT + 255) / 256, 256, 0, stream>>>(e_dm_src, e_dm_dst, e_am_src, e_am_dst,
                                                      cursor, adj);

    // ---- fold relation matrices (1 launch) ----
    {
        F4 f4{};
        f4.W[0] = Wk_d; f4.b[0] = bk_d; f4.a[0] = a_dm; f4.Wf[0] = Wf_k_dm; f4.bf[0] = bf_k_dm;
        f4.W[1] = Wv_d; f4.b[1] = bv_d; f4.a[1] = m_dm; f4.Wf[1] = Wf_v_dm; f4.bf[1] = bf_v_dm;
        f4.W[2] = Wk_a; f4.b[2] = bk_a; f4.a[2] = a_am; f4.Wf[2] = Wf_k_am; f4.bf[2] = bf_k_am;
        f4.W[3] = Wv_a; f4.b[3] = bv_a; f4.a[3] = m_am; f4.Wf[3] = Wf_v_am; f4.bf[3] = bf_v_am;
        fold_w4<<<dim3(257, 4), 256, 0, stream>>>(f4);
    }
    // ---- pack all B matrices to fragment order (1 launch) ----
    {
        PMulti pm{};
        pm.nd = 9;
        int b0 = 0;
        pm.d[0] = {W_in_m,  Bt_in_m, FIN, b0}; b0 += 32;
        pm.d[1] = {W_in_d,  Bt_in_d, FIN, b0}; b0 += 32;
        pm.d[2] = {W_in_a,  Bt_in_a, FIN, b0}; b0 += 32;
        pm.d[3] = {Wq_m,    Bt_q_m,  HID, b0}; b0 += 8;
        pm.d[4] = {Wf_k_dm, Bt_k_dm, HID, b0}; b0 += 8;
        pm.d[5] = {Wf_v_dm, Bt_v_dm, HID, b0}; b0 += 8;
        pm.d[6] = {Wf_k_am, Bt_k_am, HID, b0}; b0 += 8;
        pm.d[7] = {Wf_v_am, Bt_v_am, HID, b0}; b0 += 8;
        pm.d[8] = {Wa_m,    Bt_a_m,  HID, b0}; b0 += 8;
        wt_pack<<<b0, 256, 0, stream>>>(pm);
    }

    int bm_m = (NM + GBM - 1) / GBM;  // 391
    int bm_d = (ND + GBM - 1) / GBM;  // 79
    int bm_a = (NA + GBM - 1) / GBM;  // 196

    // launch (a): input projections, K=1024
    {
        GMulti mu{};
        mu.nd = 3;
        mu.d[0] = {x_movie,    Bt_in_m, b_in_m, h_m, nullptr, nullptr, NM, FIN, 0, 0, 0};
        mu.d[1] = {x_director, Bt_in_d, b_in_d, h_d, nullptr, nullptr, ND, FIN, 0, 0, bm_m};
        mu.d[2] = {x_actor,    Bt_in_a, b_in_a, h_a, nullptr, nullptr, NA, FIN, 0, 0, bm_m + bm_d};
        gemm_mfma<<<bm_m + bm_d + bm_a, 512, 0, stream>>>(mu);
    }
    // launch (b): q/k/v projections, K=256 (kt/vt output bf16)
    {
        GMulti mu{};
        mu.nd = 5;
        int b0 = 0;
        mu.d[0] = {h_m, Bt_q_m,  bq_m,    q_m,            nullptr, nullptr, NM, HID, 0, 0, b0}; b0 += bm_m;
        mu.d[1] = {h_d, Bt_k_dm, bf_k_dm, (float*)kt_dm,  nullptr, nullptr, ND, HID, 0, 1, b0}; b0 += bm_d;
        mu.d[2] = {h_d, Bt_v_dm, bf_v_dm, (float*)vt_dm,  nullptr, nullptr, ND, HID, 0, 1, b0}; b0 += bm_d;
        mu.d[3] = {h_a, Bt_k_am, bf_k_am, (float*)kt_am,  nullptr, nullptr, NA, HID, 0, 1, b0}; b0 += bm_a;
        mu.d[4] = {h_a, Bt_v_am, bf_v_am, (float*)vt_am,  nullptr, nullptr, NA, HID, 0, 1, b0}; b0 += bm_a;
        gemm_mfma<<<b0, 512, 0, stream>>>(mu);
    }

    // fused per-destination aggregation
    agg_fused<<<NM, 256, 0, stream>>>(rowptr, adj, q_m, kt_all, vt_all, p_dm, p_am, agg);

    // launch (c): out_movie = beta*gelu(agg@Wa+ba)+(1-beta)*h_m  (into q_m)
    {
        GMulti mu{};
        mu.nd = 1;
        mu.d[0] = {agg, Bt_a_m, ba_m, q_m, h_m, skip_m, NM, HID, 1, 0, 0};
        gemm_mfma<<<bm_m, 512, 0, stream>>>(mu);
    }

    // classifier
    classifier<<<256, 256, 0, stream>>>(q_m, W_out, b_out, (float*)d_out, NM);
}